// Round 12
// baseline (401.579 us; speedup 1.0000x reference)
//
#include <hip/hip_runtime.h>
#include <hip/hip_bf16.h>

typedef __bf16 bf16_t;
typedef __attribute__((ext_vector_type(8))) __bf16 bf16x8;
typedef __attribute__((ext_vector_type(4))) float floatx4;

#define BM 128

enum { EPI_NONE = 0, EPI_RESID, EPI_BIAS_RELU, EPI_BIAS_RESID, EPI_QL2, EPI_PART };

__device__ __forceinline__ void gld_lds16(const bf16_t* g, bf16_t* l) {
  __builtin_amdgcn_global_load_lds(
      (__attribute__((address_space(1))) void*)(g),
      (__attribute__((address_space(3))) void*)(l), 16, 0, 0);
}

// Swizzled DMA staging: LDS slot ci=(row,cc) receives GLOBAL granule cc^(row&7).
template<int ROWS, int COLS>
__device__ __forceinline__ void stage_swz(const bf16_t* g, int ld, bf16_t* lds, int tid) {
  constexpr int G = COLS / 8;
  #pragma unroll
  for (int i = 0; i < ROWS * G / 256; ++i) {
    int ci = i * 256 + tid;
    int row = ci / G, cc = ci % G;
    int gg = (G == 8) ? (cc ^ (row & 7)) : ((cc & 8) | ((cc & 7) ^ (row & 7)));
    gld_lds16(g + (size_t)row * ld + gg * 8, lds + ci * 8);
  }
}

// ======== core: 128x128 tile, BK=64, both sides bf16 DMA ========
__device__ __forceinline__ void core128(const bf16_t* __restrict__ Ag,
                                        const bf16_t* __restrict__ Bg,
                                        int K, int ldb,
                                        bf16_t* As, bf16_t* Bs,
                                        floatx4 acc[4][4]) {
  const int tid = threadIdx.x;
  const int wid = tid >> 6, lane = tid & 63;
  const int wm = (wid >> 1) * 64, wn = (wid & 1) * 64;
  const int m16 = lane & 15, quad = lane >> 4;
  const int r7 = m16 & 7;
  for (int k0 = 0; k0 < K; k0 += 64) {
    stage_swz<128, 64>(Ag + k0, K, As, tid);
    stage_swz<128, 64>(Bg + k0, ldb, Bs, tid);
    __syncthreads();
    #pragma unroll
    for (int ks = 0; ks < 2; ++ks) {
      const int gi = ks * 4 + quad;
      const int slot = gi ^ r7;
      bf16x8 af[4], bfr[4];
      #pragma unroll
      for (int mt = 0; mt < 4; ++mt)
        af[mt] = *(const bf16x8*)&As[((wm + mt * 16 + m16) * 8 + slot) * 8];
      #pragma unroll
      for (int nt = 0; nt < 4; ++nt)
        bfr[nt] = *(const bf16x8*)&Bs[((wn + nt * 16 + m16) * 8 + slot) * 8];
      #pragma unroll
      for (int mt = 0; mt < 4; ++mt)
        #pragma unroll
        for (int nt = 0; nt < 4; ++nt)
          acc[mt][nt] = __builtin_amdgcn_mfma_f32_16x16x32_bf16(af[mt], bfr[nt], acc[mt][nt], 0, 0, 0);
    }
    __syncthreads();
  }
}

// ---- 128x128 bf16 GEMM (W1: bias+relu) ----
template<int EPI>
__global__ __launch_bounds__(256)
void gemm128(const bf16_t* __restrict__ A, const bf16_t* __restrict__ B,
             bf16_t* __restrict__ C, const float* __restrict__ bias,
             int N, int K) {
  __shared__ bf16_t As[BM * 64];
  __shared__ bf16_t Bs[BM * 64];
  const int tid = threadIdx.x;
  const int wid = tid >> 6, lane = tid & 63;
  const int wm = (wid >> 1) * 64, wn = (wid & 1) * 64;
  const int m16 = lane & 15, quad = lane >> 4;
  const int m0 = blockIdx.y * BM, n0 = blockIdx.x * BM;
  floatx4 acc[4][4];
  const floatx4 vzero = {0.f, 0.f, 0.f, 0.f};
  #pragma unroll
  for (int mt = 0; mt < 4; ++mt)
    #pragma unroll
    for (int nt = 0; nt < 4; ++nt) acc[mt][nt] = vzero;
  core128(A + (size_t)m0 * K, B + (size_t)n0 * K, K, K, As, Bs, acc);
  #pragma unroll
  for (int mt = 0; mt < 4; ++mt)
    #pragma unroll
    for (int nt = 0; nt < 4; ++nt) {
      const int gcol = n0 + wn + nt * 16 + m16;
      float bv = (EPI == EPI_BIAS_RELU) ? bias[gcol] : 0.f;
      #pragma unroll
      for (int r = 0; r < 4; ++r) {
        const int grow = m0 + wm + mt * 16 + quad * 4 + r;
        float v = acc[mt][nt][r];
        if (EPI == EPI_BIAS_RELU) { v += bv; v = fmaxf(v, 0.f); }
        C[(size_t)grow * N + gcol] = (bf16_t)v;
      }
    }
}

// ---- fused QKV; Q scaled 1/8; V transposed ----
__global__ __launch_bounds__(256)
void gemm_qkv(const bf16_t* __restrict__ X, const bf16_t* __restrict__ Wb,
              bf16_t* __restrict__ Qo, bf16_t* __restrict__ Ko, bf16_t* __restrict__ Vt) {
  __shared__ bf16_t As[BM * 64];
  __shared__ bf16_t Bs[BM * 64];
  const int tid = threadIdx.x;
  const int wid = tid >> 6, lane = tid & 63;
  const int wm = (wid >> 1) * 64, wn = (wid & 1) * 64;
  const int m16 = lane & 15, quad = lane >> 4;
  const int m0 = blockIdx.y * BM, n0 = blockIdx.x * BM;
  const int sel = blockIdx.z;
  const bf16_t* B = Wb + (size_t)sel * 1024 * 1024;
  floatx4 acc[4][4];
  const floatx4 vzero = {0.f, 0.f, 0.f, 0.f};
  #pragma unroll
  for (int mt = 0; mt < 4; ++mt)
    #pragma unroll
    for (int nt = 0; nt < 4; ++nt) acc[mt][nt] = vzero;
  core128(X + (size_t)m0 * 1024, B + (size_t)n0 * 1024, 1024, 1024, As, Bs, acc);
  if (sel < 2) {
    bf16_t* C = sel ? Ko : Qo;
    const float sc = sel ? 1.f : 0.125f;
    #pragma unroll
    for (int mt = 0; mt < 4; ++mt)
      #pragma unroll
      for (int nt = 0; nt < 4; ++nt) {
        const int gcol = n0 + wn + nt * 16 + m16;
        #pragma unroll
        for (int r = 0; r < 4; ++r) {
          const int grow = m0 + wm + mt * 16 + quad * 4 + r;
          C[(size_t)grow * 1024 + gcol] = (bf16_t)(acc[mt][nt][r] * sc);
        }
      }
  } else {
    #pragma unroll
    for (int mt = 0; mt < 4; ++mt) {
      const int grow0 = m0 + wm + mt * 16 + quad * 4;
      const int b = grow0 >> 10, s = grow0 & 1023;
      #pragma unroll
      for (int nt = 0; nt < 4; ++nt) {
        const int gcol = n0 + wn + nt * 16 + m16;
        const int h = gcol >> 6, d = gcol & 63;
        #pragma unroll
        for (int r = 0; r < 4; ++r)
          Vt[(((size_t)b * 16 + h) * 64 + d) * 1024 + s + r] = (bf16_t)acc[mt][nt][r];
      }
    }
  }
}

// ======== 128x64 tile, BK=128, swizzled DMA, XCD decode, optional split-K ========
// ksplit = gridDim.x / (mblocks*nblocks). kh picks the K-half; EPI_PART writes
// bf16 partials to (kh ? part1 : Cv).
template<int EPI, bool OUTF32>
__global__ __launch_bounds__(256)
void gemm64(const bf16_t* __restrict__ A, const bf16_t* __restrict__ B,
            void* __restrict__ Cv, bf16_t* __restrict__ part1,
            const bf16_t* __restrict__ resid, const float* __restrict__ bias,
            const bf16_t* __restrict__ z, const float* __restrict__ zw,
            int N, int K, int ldb, int boff, int mblocks, int nblocks) {
  __shared__ bf16_t As[BM * 128];
  __shared__ bf16_t Bs[64 * 128];
  const int tid = threadIdx.x;
  const int wid = tid >> 6, lane = tid & 63;
  const int wm = (wid >> 1) * 64, wn = (wid & 1) * 32;
  const int m16 = lane & 15, quad = lane >> 4;
  const int r7 = m16 & 7;
  const int id = blockIdx.x;
  const int m0 = (id % mblocks) * BM;
  const int rest = id / mblocks;
  const int n0 = (rest % nblocks) * 64;
  const int kh = rest / nblocks;
  const int ksplit = gridDim.x / (mblocks * nblocks);
  const int Keff = K / ksplit;
  const bf16_t* Ag = A + (size_t)m0 * K + (size_t)kh * Keff;
  const bf16_t* Bg = B + (size_t)n0 * ldb + boff + (size_t)kh * Keff;
  floatx4 acc[4][2];
  const floatx4 vzero = {0.f, 0.f, 0.f, 0.f};
  #pragma unroll
  for (int mt = 0; mt < 4; ++mt)
    #pragma unroll
    for (int nt = 0; nt < 2; ++nt) acc[mt][nt] = vzero;
  for (int k0 = 0; k0 < Keff; k0 += 128) {
    stage_swz<128, 128>(Ag + k0, K, As, tid);
    stage_swz<64, 128>(Bg + k0, ldb, Bs, tid);
    __syncthreads();
    #pragma unroll
    for (int ks = 0; ks < 4; ++ks) {
      const int gi = ks * 4 + quad;
      const int slot = (gi & 8) | ((gi & 7) ^ r7);
      bf16x8 af[4], bfr[2];
      #pragma unroll
      for (int mt = 0; mt < 4; ++mt)
        af[mt] = *(const bf16x8*)&As[((wm + mt * 16 + m16) * 16 + slot) * 8];
      #pragma unroll
      for (int nt = 0; nt < 2; ++nt)
        bfr[nt] = *(const bf16x8*)&Bs[((wn + nt * 16 + m16) * 16 + slot) * 8];
      #pragma unroll
      for (int mt = 0; mt < 4; ++mt)
        #pragma unroll
        for (int nt = 0; nt < 2; ++nt)
          acc[mt][nt] = __builtin_amdgcn_mfma_f32_16x16x32_bf16(af[mt], bfr[nt], acc[mt][nt], 0, 0, 0);
    }
    __syncthreads();
  }
  bf16_t* Cp = (EPI == EPI_PART && kh) ? part1 : (bf16_t*)Cv;
  #pragma unroll
  for (int mt = 0; mt < 4; ++mt)
    #pragma unroll
    for (int nt = 0; nt < 2; ++nt) {
      const int gcol = n0 + wn + nt * 16 + m16;
      float bv = 0.f;
      if (EPI == EPI_BIAS_RESID || EPI == EPI_QL2) bv = bias[gcol];
      #pragma unroll
      for (int r = 0; r < 4; ++r) {
        const int grow = m0 + wm + mt * 16 + quad * 4 + r;
        float v = acc[mt][nt][r];
        if (EPI == EPI_RESID) v += (float)resid[(size_t)grow * N + gcol];
        if (EPI == EPI_BIAS_RESID) v += bv + (float)resid[(size_t)grow * N + gcol];
        if (EPI == EPI_QL2) {
          float s = 0.f;
          #pragma unroll
          for (int u = 0; u < 8; ++u)
            s += (float)z[(size_t)grow * 8 + u] * zw[(size_t)gcol * 1032 + u];
          v += bv + s;
        }
        if (OUTF32) ((float*)Cv)[(size_t)grow * N + gcol] = v;
        else        Cp[(size_t)grow * N + gcol] = (bf16_t)v;
      }
    }
}

// ======== flash attention (R9, verified) ========
__global__ __launch_bounds__(256)
void attn_kernel(const bf16_t* __restrict__ Q, const bf16_t* __restrict__ Kb,
                 const bf16_t* __restrict__ Vt, bf16_t* __restrict__ O) {
  __shared__ bf16_t Qs[64 * 64];
  __shared__ bf16_t Ks[128 * 64];
  __shared__ bf16_t Vs[64 * 128];
  __shared__ bf16_t Ps[4][16 * 128];
  const int tid = threadIdx.x;
  const int wid = tid >> 6, lane = tid & 63;
  const int m16 = lane & 15, quad = lane >> 4;
  const int qt = blockIdx.x, bh = blockIdx.y;
  const int b = bh >> 4, h = bh & 15;
  const size_t qbase = ((size_t)(b * 1024 + qt * 64)) * 1024 + h * 64;
  #pragma unroll
  for (int i = 0; i < 2; ++i) {
    int ci = i * 256 + tid;
    int row = ci >> 3, cc = ci & 7;
    *(bf16x8*)&Qs[row * 64 + ((cc ^ (row & 7)) * 8)] =
        *(const bf16x8*)&Q[qbase + (size_t)row * 1024 + cc * 8];
  }
  __syncthreads();
  const int qm = wid * 16 + m16;
  bf16x8 qf0 = *(const bf16x8*)&Qs[qm * 64 + ((quad ^ (qm & 7)) * 8)];
  bf16x8 qf1 = *(const bf16x8*)&Qs[qm * 64 + (((4 + quad) ^ (qm & 7)) * 8)];
  floatx4 oacc[4];
  float rs[4];
  const floatx4 vzero = {0.f, 0.f, 0.f, 0.f};
  #pragma unroll
  for (int dt = 0; dt < 4; ++dt) oacc[dt] = vzero;
  #pragma unroll
  for (int r = 0; r < 4; ++r) rs[r] = 0.f;
  const size_t kbase = ((size_t)(b * 1024)) * 1024 + h * 64;
  const size_t vbase = ((size_t)bh * 64) * 1024;
  for (int kt = 0; kt < 8; ++kt) {
    __syncthreads();
    #pragma unroll
    for (int i = 0; i < 4; ++i) {
      int ci = i * 256 + tid;
      int row = ci >> 3, cc = ci & 7;
      *(bf16x8*)&Ks[row * 64 + ((cc ^ (row & 7)) * 8)] =
          *(const bf16x8*)&Kb[kbase + (size_t)(kt * 128 + row) * 1024 + cc * 8];
    }
    #pragma unroll
    for (int i = 0; i < 4; ++i) {
      int ci = i * 256 + tid;
      int dr = ci >> 4, cc = ci & 15;
      int gs = (cc & 8) | ((cc & 7) ^ (dr & 7));
      *(bf16x8*)&Vs[dr * 128 + gs * 8] =
          *(const bf16x8*)&Vt[vbase + (size_t)dr * 1024 + kt * 128 + cc * 8];
    }
    __syncthreads();
    floatx4 sa[8];
    #pragma unroll
    for (int nt = 0; nt < 8; ++nt) sa[nt] = vzero;
    #pragma unroll
    for (int nt = 0; nt < 8; ++nt) {
      const int n = nt * 16 + m16;
      bf16x8 kf0 = *(const bf16x8*)&Ks[n * 64 + ((quad ^ (n & 7)) * 8)];
      bf16x8 kf1 = *(const bf16x8*)&Ks[n * 64 + (((4 + quad) ^ (n & 7)) * 8)];
      sa[nt] = __builtin_amdgcn_mfma_f32_16x16x32_bf16(qf0, kf0, sa[nt], 0, 0, 0);
      sa[nt] = __builtin_amdgcn_mfma_f32_16x16x32_bf16(qf1, kf1, sa[nt], 0, 0, 0);
    }
    #pragma unroll
    for (int nt = 0; nt < 8; ++nt)
      #pragma unroll
      for (int r = 0; r < 4; ++r) {
        float pv = __expf(sa[nt][r]);
        rs[r] += pv;
        const int prow = quad * 4 + r;
        const int g = nt * 2 + (m16 >> 3);
        const int gs = (g & 8) | ((g & 7) ^ (prow & 7));
        Ps[wid][prow * 128 + gs * 8 + (m16 & 7)] = (bf16_t)pv;
      }
    bf16x8 pf[4];
    #pragma unroll
    for (int ksub = 0; ksub < 4; ++ksub) {
      const int g = ksub * 4 + quad;
      const int gs = (g & 8) | ((g & 7) ^ (m16 & 7));
      pf[ksub] = *(const bf16x8*)&Ps[wid][m16 * 128 + gs * 8];
    }
    #pragma unroll
    for (int dt = 0; dt < 4; ++dt) {
      const int n = dt * 16 + m16;
      #pragma unroll
      for (int ksub = 0; ksub < 4; ++ksub) {
        const int g = ksub * 4 + quad;
        const int gs = (g & 8) | ((g & 7) ^ (n & 7));
        bf16x8 vf = *(const bf16x8*)&Vs[n * 128 + gs * 8];
        oacc[dt] = __builtin_amdgcn_mfma_f32_16x16x32_bf16(pf[ksub], vf, oacc[dt], 0, 0, 0);
      }
    }
  }
  #pragma unroll
  for (int r = 0; r < 4; ++r) {
    rs[r] += __shfl_xor(rs[r], 1);
    rs[r] += __shfl_xor(rs[r], 2);
    rs[r] += __shfl_xor(rs[r], 4);
    rs[r] += __shfl_xor(rs[r], 8);
  }
  const size_t obase = ((size_t)(b * 1024 + qt * 64 + wid * 16)) * 1024 + h * 64;
  #pragma unroll
  for (int dt = 0; dt < 4; ++dt)
    #pragma unroll
    for (int r = 0; r < 4; ++r)
      O[obase + (size_t)(quad * 4 + r) * 1024 + dt * 16 + m16] = (bf16_t)(oacc[dt][r] / rs[r]);
}

// ---------------- segmented fp32 -> bf16 conversion ----------------
struct Segs {
  const float* s[5];
  bf16_t* d[5];
  int n8[5];
};
__global__ __launch_bounds__(256)
void conv_multi(Segs sg) {
  const int zz = blockIdx.z;
  const float* in = sg.s[zz];
  bf16_t* out = sg.d[zz];
  const int n8 = sg.n8[zz];
  for (int i = blockIdx.x * 256 + threadIdx.x; i < n8; i += gridDim.x * 256) {
    const float* p = in + (size_t)i * 8;
    floatx4 a = *(const floatx4*)p;
    floatx4 b = *(const floatx4*)(p + 4);
    bf16x8 o;
    #pragma unroll
    for (int j = 0; j < 4; ++j) { o[j] = (bf16_t)a[j]; o[4 + j] = (bf16_t)b[j]; }
    *(bf16x8*)(out + (size_t)i * 8) = o;
  }
}

// ---------------- LN1 with split-K combine: in = p0 + p1 + resid ----------------
__global__ __launch_bounds__(256)
void ln_combine(const bf16_t* __restrict__ p0, const bf16_t* __restrict__ p1,
                const bf16_t* __restrict__ resid,
                const float* __restrict__ g, const float* __restrict__ b,
                bf16_t* __restrict__ out) {
  const int row = blockIdx.x * 4 + (threadIdx.x >> 6);
  const int lane = threadIdx.x & 63;
  const size_t base = (size_t)row * 1024 + lane * 16;
  bf16x8 a0 = *(const bf16x8*)&p0[base];
  bf16x8 a1 = *(const bf16x8*)&p0[base + 8];
  bf16x8 b0 = *(const bf16x8*)&p1[base];
  bf16x8 b1 = *(const bf16x8*)&p1[base + 8];
  bf16x8 c0 = *(const bf16x8*)&resid[base];
  bf16x8 c1 = *(const bf16x8*)&resid[base + 8];
  float f[16];
  #pragma unroll
  for (int j = 0; j < 8; ++j) {
    f[j]     = (float)a0[j] + (float)b0[j] + (float)c0[j];
    f[8 + j] = (float)a1[j] + (float)b1[j] + (float)c1[j];
  }
  float s = 0.f, ss = 0.f;
  #pragma unroll
  for (int j = 0; j < 16; ++j) { s += f[j]; ss += f[j] * f[j]; }
  #pragma unroll
  for (int off = 1; off < 64; off <<= 1) { s += __shfl_xor(s, off); ss += __shfl_xor(ss, off); }
  const float m = s * (1.f / 1024.f);
  const float inv_sd = rsqrtf(ss * (1.f / 1024.f) - m * m + 1e-5f);
  const float* gp = g + lane * 16;
  const float* bp = b + lane * 16;
  bf16x8 o0, o1;
  #pragma unroll
  for (int j = 0; j < 8; ++j) o0[j] = (bf16_t)((f[j] - m) * inv_sd * gp[j] + bp[j]);
  #pragma unroll
  for (int j = 0; j < 8; ++j) o1[j] = (bf16_t)((f[8 + j] - m) * inv_sd * gp[8 + j] + bp[8 + j]);
  *(bf16x8*)&out[base] = o0;
  *(bf16x8*)&out[base + 8] = o1;
}

// ---- fused: (W2 split-K combine + b2 + resid) -> LN2 -> x2; quantum -> z; ql2w conv ----
__global__ __launch_bounds__(256)
void ln2_quantum(const bf16_t* __restrict__ p0, const bf16_t* __restrict__ p1,
                 const bf16_t* __restrict__ resid, const float* __restrict__ bias,
                 const float* __restrict__ g, const float* __restrict__ b,
                 bf16_t* __restrict__ x2,
                 const float* __restrict__ qw1, const float* __restrict__ qb1,
                 const float* __restrict__ qwt, bf16_t* __restrict__ zout,
                 const float* __restrict__ ql2w, bf16_t* __restrict__ ql2wb) {
  if (blockIdx.z == 1) {
    const int n8 = 1024 * 1032 / 8;
    for (int i = blockIdx.x * 256 + threadIdx.x; i < n8; i += gridDim.x * 256) {
      const float* p = ql2w + (size_t)i * 8;
      floatx4 a = *(const floatx4*)p;
      floatx4 bb = *(const floatx4*)(p + 4);
      bf16x8 o;
      #pragma unroll
      for (int j = 0; j < 4; ++j) { o[j] = (bf16_t)a[j]; o[4 + j] = (bf16_t)bb[j]; }
      *(bf16x8*)(ql2wb + (size_t)i * 8) = o;
    }
    return;
  }
  const int row = blockIdx.x * 4 + (threadIdx.x >> 6);
  const int lane = threadIdx.x & 63;
  const size_t base = (size_t)row * 1024 + lane * 16;
  bf16x8 a0 = *(const bf16x8*)&p0[base];
  bf16x8 a1 = *(const bf16x8*)&p0[base + 8];
  bf16x8 b0 = *(const bf16x8*)&p1[base];
  bf16x8 b1 = *(const bf16x8*)&p1[base + 8];
  bf16x8 c0 = *(const bf16x8*)&resid[base];
  bf16x8 c1 = *(const bf16x8*)&resid[base + 8];
  const float* bsp = bias + lane * 16;
  float f[16];
  #pragma unroll
  for (int j = 0; j < 8; ++j) {
    f[j]     = (float)a0[j] + (float)b0[j] + (float)c0[j] + bsp[j];
    f[8 + j] = (float)a1[j] + (float)b1[j] + (float)c1[j] + bsp[8 + j];
  }
  float s = 0.f, ss = 0.f;
  #pragma unroll
  for (int j = 0; j < 16; ++j) { s += f[j]; ss += f[j] * f[j]; }
  #pragma unroll
  for (int off = 1; off < 64; off <<= 1) { s += __shfl_xor(s, off); ss += __shfl_xor(ss, off); }
  const float m = s * (1.f / 1024.f);
  const float inv_sd = rsqrtf(ss * (1.f / 1024.f) - m * m + 1e-5f);
  const float* gp = g + lane * 16;
  const float* bp = b + lane * 16;
  bf16x8 o0, o1;
  #pragma unroll
  for (int j = 0; j < 8; ++j) o0[j] = (bf16_t)((f[j] - m) * inv_sd * gp[j] + bp[j]);
  #pragma unroll
  for (int j = 0; j < 8; ++j) o1[j] = (bf16_t)((f[8 + j] - m) * inv_sd * gp[8 + j] + bp[8 + j]);
  *(bf16x8*)&x2[base] = o0;
  *(bf16x8*)&x2[base + 8] = o1;
  float th[8];
  #pragma unroll
  for (int qq = 0; qq < 8; ++qq) {
    const float* wp = qw1 + (size_t)qq * 1024 + lane * 16;
    float sdot = 0.f;
    #pragma unroll
    for (int j = 0; j < 8; ++j)
      sdot += (float)o0[j] * wp[j] + (float)o1[j] * wp[8 + j];
    #pragma unroll
    for (int off = 1; off < 64; off <<= 1) sdot += __shfl_xor(sdot, off);
    th[qq] = sdot + qb1[qq] + qwt[qq];
  }
  if (lane == 0) {
    float c[8];
    #pragma unroll
    for (int qq = 0; qq < 8; ++qq) c[qq] = cosf(th[qq]);
    float z0 = 1.f;
    #pragma unroll
    for (int u = 1; u < 8; ++u) z0 *= c[u];
    zout[(size_t)row * 8 + 0] = (bf16_t)z0;
    float pp = c[0];
    #pragma unroll
    for (int w = 1; w < 8; ++w) { pp *= c[w]; zout[(size_t)row * 8 + w] = (bf16_t)pp; }
  }
}

extern "C" void kernel_launch(void* const* d_in, const int* in_sizes, int n_in,
                              void* d_out, int out_size, void* d_ws, size_t ws_size,
                              hipStream_t stream) {
  const float* x    = (const float*)d_in[0];
  const float* Wq   = (const float*)d_in[1];
  const float* Wk   = (const float*)d_in[2];
  const float* Wv   = (const float*)d_in[3];
  const float* Wo   = (const float*)d_in[4];
  const float* ln1g = (const float*)d_in[5];
  const float* ln1b = (const float*)d_in[6];
  const float* W1   = (const float*)d_in[7];
  const float* b1   = (const float*)d_in[8];
  const float* W2   = (const float*)d_in[9];
  const float* b2   = (const float*)d_in[10];
  const float* ln2g = (const float*)d_in[11];
  const float* ln2b = (const float*)d_in[12];
  const float* qw1  = (const float*)d_in[13];
  const float* qb1  = (const float*)d_in[14];
  const float* qwt  = (const float*)d_in[15];
  const float* ql2w = (const float*)d_in[16];
  const float* ql2b = (const float*)d_in[17];
  bf16_t* ws = (bf16_t*)d_ws;

  const size_t T = (size_t)4096 * 1024;
  const size_t M1 = (size_t)1024 * 1024;
  bf16_t* outlo = (bf16_t*)d_out;
  bf16_t* outhi = outlo + T;

  bf16_t* xb    = ws;            // x bf16; resid for LN1; then W2 partial p0
  bf16_t* kb    = ws + T;        // K; Wo partial p1; then w2b; then z
  bf16_t* vt    = ws + 2 * T;    // V^T; then w1b; then W2 partial p1 / x2
  bf16_t* ff    = ws + 3 * T;    // wqkvb+wob; then FFN hidden; then ql2wb
  bf16_t* wqkvb = ff;
  bf16_t* wob   = ff + 3 * M1;
  bf16_t* w1b   = vt;
  bf16_t* w2b   = kb;
  bf16_t* ql2wb = ff;
  bf16_t* q     = outlo;
  bf16_t* o     = outhi;
  bf16_t* x1    = outhi;         // LN1 out (o dead)
  bf16_t* x2    = vt;            // LN2 out (in-place over W2 p1)
  bf16_t* z     = kb;

  {
    Segs sg;
    sg.s[0] = x;  sg.d[0] = xb;            sg.n8[0] = (int)(T / 8);
    sg.s[1] = Wq; sg.d[1] = wqkvb;         sg.n8[1] = (int)(M1 / 8);
    sg.s[2] = Wk; sg.d[2] = wqkvb + M1;    sg.n8[2] = (int)(M1 / 8);
    sg.s[3] = Wv; sg.d[3] = wqkvb + 2*M1;  sg.n8[3] = (int)(M1 / 8);
    sg.s[4] = Wo; sg.d[4] = wob;           sg.n8[4] = (int)(M1 / 8);
    conv_multi<<<dim3(512, 1, 5), 256, 0, stream>>>(sg);
  }
  gemm_qkv<<<dim3(8, 32, 3), 256, 0, stream>>>(xb, wqkvb, q, kb, vt);
  attn_kernel<<<dim3(16, 64), 256, 0, stream>>>(q, kb, vt, o);
  // Wo split-K=2: partials to outlo (q dead) + kb (K dead); combine in LN1.
  gemm64<EPI_PART, false><<<1024, 256, 0, stream>>>(
      o, wob, outlo, kb, nullptr, nullptr, nullptr, nullptr, 1024, 1024, 1024, 0, 32, 16);
  ln_combine<<<1024, 256, 0, stream>>>(outlo, kb, xb, ln1g, ln1b, x1);
  {
    Segs sg;
    sg.s[0] = W1; sg.d[0] = w1b; sg.n8[0] = (int)(T / 8);
    sg.s[1] = W2; sg.d[1] = w2b; sg.n8[1] = (int)(T / 8);
    sg.s[2] = nullptr; sg.d[2] = nullptr; sg.n8[2] = 0;
    sg.s[3] = nullptr; sg.d[3] = nullptr; sg.n8[3] = 0;
    sg.s[4] = nullptr; sg.d[4] = nullptr; sg.n8[4] = 0;
    conv_multi<<<dim3(1024, 1, 2), 256, 0, stream>>>(sg);
  }
  gemm128<EPI_BIAS_RELU><<<dim3(32, 32), 256, 0, stream>>>(x1, w1b, ff, b1, 4096, 1024);
  // W2 split-K=2: partials to xb (x dead) + vt (w1b dead); combine+b2+resid in LN2.
  gemm64<EPI_PART, false><<<1024, 256, 0, stream>>>(
      ff, w2b, xb, vt, nullptr, nullptr, nullptr, nullptr, 1024, 4096, 4096, 0, 32, 16);
  ln2_quantum<<<dim3(1024, 1, 2), 256, 0, stream>>>(
      xb, vt, x1, b2, ln2g, ln2b, x2, qw1, qb1, qwt, z, ql2w, ql2wb);
  gemm64<EPI_QL2, true><<<512, 256, 0, stream>>>(
      x2, ql2wb, d_out, nullptr, nullptr, ql2b, z, ql2w, 1024, 1024, 1032, 8, 32, 16);
}

// Round 14
// 398.254 us; speedup vs baseline: 1.0083x; 1.0083x over previous
//
#include <hip/hip_runtime.h>
#include <hip/hip_bf16.h>

typedef __bf16 bf16_t;
typedef __attribute__((ext_vector_type(8))) __bf16 bf16x8;
typedef __attribute__((ext_vector_type(4))) float floatx4;

#define BM 128

enum { EPI_NONE = 0, EPI_RESID, EPI_BIAS_RELU, EPI_BIAS_RESID, EPI_QL2, EPI_PART };

__device__ __forceinline__ void gld_lds16(const bf16_t* g, bf16_t* l) {
  __builtin_amdgcn_global_load_lds(
      (__attribute__((address_space(1))) void*)(g),
      (__attribute__((address_space(3))) void*)(l), 16, 0, 0);
}

// Swizzled DMA staging: LDS slot ci=(row,cc) receives GLOBAL granule cc^(row&7).
template<int ROWS, int COLS>
__device__ __forceinline__ void stage_swz(const bf16_t* g, int ld, bf16_t* lds, int tid) {
  constexpr int G = COLS / 8;
  #pragma unroll
  for (int i = 0; i < ROWS * G / 256; ++i) {
    int ci = i * 256 + tid;
    int row = ci / G, cc = ci % G;
    int gg = (G == 8) ? (cc ^ (row & 7)) : ((cc & 8) | ((cc & 7) ^ (row & 7)));
    gld_lds16(g + (size_t)row * ld + gg * 8, lds + ci * 8);
  }
}

// ======== core: 128x128 tile, BK=64, both sides bf16 DMA; Kloop may be < lda ========
__device__ __forceinline__ void core128(const bf16_t* __restrict__ Ag,
                                        const bf16_t* __restrict__ Bg,
                                        int Kloop, int lda, int ldb,
                                        bf16_t* As, bf16_t* Bs,
                                        floatx4 acc[4][4]) {
  const int tid = threadIdx.x;
  const int wid = tid >> 6, lane = tid & 63;
  const int wm = (wid >> 1) * 64, wn = (wid & 1) * 64;
  const int m16 = lane & 15, quad = lane >> 4;
  const int r7 = m16 & 7;
  for (int k0 = 0; k0 < Kloop; k0 += 64) {
    stage_swz<128, 64>(Ag + k0, lda, As, tid);
    stage_swz<128, 64>(Bg + k0, ldb, Bs, tid);
    __syncthreads();
    #pragma unroll
    for (int ks = 0; ks < 2; ++ks) {
      const int gi = ks * 4 + quad;
      const int slot = gi ^ r7;
      bf16x8 af[4], bfr[4];
      #pragma unroll
      for (int mt = 0; mt < 4; ++mt)
        af[mt] = *(const bf16x8*)&As[((wm + mt * 16 + m16) * 8 + slot) * 8];
      #pragma unroll
      for (int nt = 0; nt < 4; ++nt)
        bfr[nt] = *(const bf16x8*)&Bs[((wn + nt * 16 + m16) * 8 + slot) * 8];
      #pragma unroll
      for (int mt = 0; mt < 4; ++mt)
        #pragma unroll
        for (int nt = 0; nt < 4; ++nt)
          acc[mt][nt] = __builtin_amdgcn_mfma_f32_16x16x32_bf16(af[mt], bfr[nt], acc[mt][nt], 0, 0, 0);
    }
    __syncthreads();
  }
}

// ---- 128x128 bf16 GEMM (W1: bias+relu) ----
template<int EPI>
__global__ __launch_bounds__(256)
void gemm128(const bf16_t* __restrict__ A, const bf16_t* __restrict__ B,
             bf16_t* __restrict__ C, const float* __restrict__ bias,
             int N, int K) {
  __shared__ bf16_t As[BM * 64];
  __shared__ bf16_t Bs[BM * 64];
  const int tid = threadIdx.x;
  const int wid = tid >> 6, lane = tid & 63;
  const int wm = (wid >> 1) * 64, wn = (wid & 1) * 64;
  const int m16 = lane & 15, quad = lane >> 4;
  const int m0 = blockIdx.y * BM, n0 = blockIdx.x * BM;
  floatx4 acc[4][4];
  const floatx4 vzero = {0.f, 0.f, 0.f, 0.f};
  #pragma unroll
  for (int mt = 0; mt < 4; ++mt)
    #pragma unroll
    for (int nt = 0; nt < 4; ++nt) acc[mt][nt] = vzero;
  core128(A + (size_t)m0 * K, B + (size_t)n0 * K, K, K, K, As, Bs, acc);
  #pragma unroll
  for (int mt = 0; mt < 4; ++mt)
    #pragma unroll
    for (int nt = 0; nt < 4; ++nt) {
      const int gcol = n0 + wn + nt * 16 + m16;
      float bv = (EPI == EPI_BIAS_RELU) ? bias[gcol] : 0.f;
      #pragma unroll
      for (int r = 0; r < 4; ++r) {
        const int grow = m0 + wm + mt * 16 + quad * 4 + r;
        float v = acc[mt][nt][r];
        if (EPI == EPI_BIAS_RELU) { v += bv; v = fmaxf(v, 0.f); }
        C[(size_t)grow * N + gcol] = (bf16_t)v;
      }
    }
}

// ---- 128x128 split-K=2, XCD-aware 1-D decode; bf16 partials to p0/p1 (Wo, W2) ----
__global__ __launch_bounds__(256)
void gemm128_sk(const bf16_t* __restrict__ A, const bf16_t* __restrict__ B,
                bf16_t* __restrict__ p0, bf16_t* __restrict__ p1,
                int N, int K, int ldb, int mblocks, int nblocks) {
  __shared__ bf16_t As[BM * 64];
  __shared__ bf16_t Bs[BM * 64];
  const int tid = threadIdx.x;
  const int wid = tid >> 6, lane = tid & 63;
  const int wm = (wid >> 1) * 64, wn = (wid & 1) * 64;
  const int m16 = lane & 15, quad = lane >> 4;
  const int id = blockIdx.x;
  const int m0 = (id % mblocks) * BM;
  const int rest = id / mblocks;
  const int n0 = (rest % nblocks) * BM;
  const int kh = rest / nblocks;
  const int Keff = K / 2;
  floatx4 acc[4][4];
  const floatx4 vzero = {0.f, 0.f, 0.f, 0.f};
  #pragma unroll
  for (int mt = 0; mt < 4; ++mt)
    #pragma unroll
    for (int nt = 0; nt < 4; ++nt) acc[mt][nt] = vzero;
  core128(A + (size_t)m0 * K + (size_t)kh * Keff,
          B + (size_t)n0 * ldb + (size_t)kh * Keff, Keff, K, ldb, As, Bs, acc);
  bf16_t* Cp = kh ? p1 : p0;
  #pragma unroll
  for (int mt = 0; mt < 4; ++mt)
    #pragma unroll
    for (int nt = 0; nt < 4; ++nt) {
      const int gcol = n0 + wn + nt * 16 + m16;
      #pragma unroll
      for (int r = 0; r < 4; ++r) {
        const int grow = m0 + wm + mt * 16 + quad * 4 + r;
        Cp[(size_t)grow * N + gcol] = (bf16_t)acc[mt][nt][r];
      }
    }
}

// ---- fused QKV; Q scaled 1/8; V transposed ----
__global__ __launch_bounds__(256)
void gemm_qkv(const bf16_t* __restrict__ X, const bf16_t* __restrict__ Wb,
              bf16_t* __restrict__ Qo, bf16_t* __restrict__ Ko, bf16_t* __restrict__ Vt) {
  __shared__ bf16_t As[BM * 64];
  __shared__ bf16_t Bs[BM * 64];
  const int tid = threadIdx.x;
  const int wid = tid >> 6, lane = tid & 63;
  const int wm = (wid >> 1) * 64, wn = (wid & 1) * 64;
  const int m16 = lane & 15, quad = lane >> 4;
  const int m0 = blockIdx.y * BM, n0 = blockIdx.x * BM;
  const int sel = blockIdx.z;
  const bf16_t* B = Wb + (size_t)sel * 1024 * 1024;
  floatx4 acc[4][4];
  const floatx4 vzero = {0.f, 0.f, 0.f, 0.f};
  #pragma unroll
  for (int mt = 0; mt < 4; ++mt)
    #pragma unroll
    for (int nt = 0; nt < 4; ++nt) acc[mt][nt] = vzero;
  core128(X + (size_t)m0 * 1024, B + (size_t)n0 * 1024, 1024, 1024, 1024, As, Bs, acc);
  if (sel < 2) {
    bf16_t* C = sel ? Ko : Qo;
    const float sc = sel ? 1.f : 0.125f;
    #pragma unroll
    for (int mt = 0; mt < 4; ++mt)
      #pragma unroll
      for (int nt = 0; nt < 4; ++nt) {
        const int gcol = n0 + wn + nt * 16 + m16;
        #pragma unroll
        for (int r = 0; r < 4; ++r) {
          const int grow = m0 + wm + mt * 16 + quad * 4 + r;
          C[(size_t)grow * 1024 + gcol] = (bf16_t)(acc[mt][nt][r] * sc);
        }
      }
  } else {
    #pragma unroll
    for (int mt = 0; mt < 4; ++mt) {
      const int grow0 = m0 + wm + mt * 16 + quad * 4;
      const int b = grow0 >> 10, s = grow0 & 1023;
      #pragma unroll
      for (int nt = 0; nt < 4; ++nt) {
        const int gcol = n0 + wn + nt * 16 + m16;
        const int h = gcol >> 6, d = gcol & 63;
        #pragma unroll
        for (int r = 0; r < 4; ++r)
          Vt[(((size_t)b * 16 + h) * 64 + d) * 1024 + s + r] = (bf16_t)acc[mt][nt][r];
      }
    }
  }
}

// ======== 128x64 tile, BK=128 (ql2 only) ========
template<int EPI, bool OUTF32>
__global__ __launch_bounds__(256)
void gemm64(const bf16_t* __restrict__ A, const bf16_t* __restrict__ B,
            void* __restrict__ Cv,
            const bf16_t* __restrict__ resid, const float* __restrict__ bias,
            const bf16_t* __restrict__ z, const float* __restrict__ zw,
            int N, int K, int ldb, int boff, int mblocks) {
  __shared__ bf16_t As[BM * 128];
  __shared__ bf16_t Bs[64 * 128];
  const int tid = threadIdx.x;
  const int wid = tid >> 6, lane = tid & 63;
  const int wm = (wid >> 1) * 64, wn = (wid & 1) * 32;
  const int m16 = lane & 15, quad = lane >> 4;
  const int r7 = m16 & 7;
  const int id = blockIdx.x;
  const int m0 = (id % mblocks) * BM, n0 = (id / mblocks) * 64;
  const bf16_t* Ag = A + (size_t)m0 * K;
  const bf16_t* Bg = B + (size_t)n0 * ldb + boff;
  floatx4 acc[4][2];
  const floatx4 vzero = {0.f, 0.f, 0.f, 0.f};
  #pragma unroll
  for (int mt = 0; mt < 4; ++mt)
    #pragma unroll
    for (int nt = 0; nt < 2; ++nt) acc[mt][nt] = vzero;
  for (int k0 = 0; k0 < K; k0 += 128) {
    stage_swz<128, 128>(Ag + k0, K, As, tid);
    stage_swz<64, 128>(Bg + k0, ldb, Bs, tid);
    __syncthreads();
    #pragma unroll
    for (int ks = 0; ks < 4; ++ks) {
      const int gi = ks * 4 + quad;
      const int slot = (gi & 8) | ((gi & 7) ^ r7);
      bf16x8 af[4], bfr[2];
      #pragma unroll
      for (int mt = 0; mt < 4; ++mt)
        af[mt] = *(const bf16x8*)&As[((wm + mt * 16 + m16) * 16 + slot) * 8];
      #pragma unroll
      for (int nt = 0; nt < 2; ++nt)
        bfr[nt] = *(const bf16x8*)&Bs[((wn + nt * 16 + m16) * 16 + slot) * 8];
      #pragma unroll
      for (int mt = 0; mt < 4; ++mt)
        #pragma unroll
        for (int nt = 0; nt < 2; ++nt)
          acc[mt][nt] = __builtin_amdgcn_mfma_f32_16x16x32_bf16(af[mt], bfr[nt], acc[mt][nt], 0, 0, 0);
    }
    __syncthreads();
  }
  #pragma unroll
  for (int mt = 0; mt < 4; ++mt)
    #pragma unroll
    for (int nt = 0; nt < 2; ++nt) {
      const int gcol = n0 + wn + nt * 16 + m16;
      float bv = 0.f;
      if (EPI == EPI_QL2) bv = bias[gcol];
      #pragma unroll
      for (int r = 0; r < 4; ++r) {
        const int grow = m0 + wm + mt * 16 + quad * 4 + r;
        float v = acc[mt][nt][r];
        if (EPI == EPI_RESID) v += (float)resid[(size_t)grow * N + gcol];
        if (EPI == EPI_QL2) {
          float s = 0.f;
          #pragma unroll
          for (int u = 0; u < 8; ++u)
            s += (float)z[(size_t)grow * 8 + u] * zw[(size_t)gcol * 1032 + u];
          v += bv + s;
        }
        if (OUTF32) ((float*)Cv)[(size_t)grow * N + gcol] = v;
        else        ((bf16_t*)Cv)[(size_t)grow * N + gcol] = (bf16_t)v;
      }
    }
}

// ======== flash attention (R9, verified) ========
__global__ __launch_bounds__(256)
void attn_kernel(const bf16_t* __restrict__ Q, const bf16_t* __restrict__ Kb,
                 const bf16_t* __restrict__ Vt, bf16_t* __restrict__ O) {
  __shared__ bf16_t Qs[64 * 64];
  __shared__ bf16_t Ks[128 * 64];
  __shared__ bf16_t Vs[64 * 128];
  __shared__ bf16_t Ps[4][16 * 128];
  const int tid = threadIdx.x;
  const int wid = tid >> 6, lane = tid & 63;
  const int m16 = lane & 15, quad = lane >> 4;
  const int qt = blockIdx.x, bh = blockIdx.y;
  const int b = bh >> 4, h = bh & 15;
  const size_t qbase = ((size_t)(b * 1024 + qt * 64)) * 1024 + h * 64;
  #pragma unroll
  for (int i = 0; i < 2; ++i) {
    int ci = i * 256 + tid;
    int row = ci >> 3, cc = ci & 7;
    *(bf16x8*)&Qs[row * 64 + ((cc ^ (row & 7)) * 8)] =
        *(const bf16x8*)&Q[qbase + (size_t)row * 1024 + cc * 8];
  }
  __syncthreads();
  const int qm = wid * 16 + m16;
  bf16x8 qf0 = *(const bf16x8*)&Qs[qm * 64 + ((quad ^ (qm & 7)) * 8)];
  bf16x8 qf1 = *(const bf16x8*)&Qs[qm * 64 + (((4 + quad) ^ (qm & 7)) * 8)];
  floatx4 oacc[4];
  float rs[4];
  const floatx4 vzero = {0.f, 0.f, 0.f, 0.f};
  #pragma unroll
  for (int dt = 0; dt < 4; ++dt) oacc[dt] = vzero;
  #pragma unroll
  for (int r = 0; r < 4; ++r) rs[r] = 0.f;
  const size_t kbase = ((size_t)(b * 1024)) * 1024 + h * 64;
  const size_t vbase = ((size_t)bh * 64) * 1024;
  for (int kt = 0; kt < 8; ++kt) {
    __syncthreads();
    #pragma unroll
    for (int i = 0; i < 4; ++i) {
      int ci = i * 256 + tid;
      int row = ci >> 3, cc = ci & 7;
      *(bf16x8*)&Ks[row * 64 + ((cc ^ (row & 7)) * 8)] =
          *(const bf16x8*)&Kb[kbase + (size_t)(kt * 128 + row) * 1024 + cc * 8];
    }
    #pragma unroll
    for (int i = 0; i < 4; ++i) {
      int ci = i * 256 + tid;
      int dr = ci >> 4, cc = ci & 15;
      int gs = (cc & 8) | ((cc & 7) ^ (dr & 7));
      *(bf16x8*)&Vs[dr * 128 + gs * 8] =
          *(const bf16x8*)&Vt[vbase + (size_t)dr * 1024 + kt * 128 + cc * 8];
    }
    __syncthreads();
    floatx4 sa[8];
    #pragma unroll
    for (int nt = 0; nt < 8; ++nt) sa[nt] = vzero;
    #pragma unroll
    for (int nt = 0; nt < 8; ++nt) {
      const int n = nt * 16 + m16;
      bf16x8 kf0 = *(const bf16x8*)&Ks[n * 64 + ((quad ^ (n & 7)) * 8)];
      bf16x8 kf1 = *(const bf16x8*)&Ks[n * 64 + (((4 + quad) ^ (n & 7)) * 8)];
      sa[nt] = __builtin_amdgcn_mfma_f32_16x16x32_bf16(qf0, kf0, sa[nt], 0, 0, 0);
      sa[nt] = __builtin_amdgcn_mfma_f32_16x16x32_bf16(qf1, kf1, sa[nt], 0, 0, 0);
    }
    #pragma unroll
    for (int nt = 0; nt < 8; ++nt)
      #pragma unroll
      for (int r = 0; r < 4; ++r) {
        float pv = __expf(sa[nt][r]);
        rs[r] += pv;
        const int prow = quad * 4 + r;
        const int g = nt * 2 + (m16 >> 3);
        const int gs = (g & 8) | ((g & 7) ^ (prow & 7));
        Ps[wid][prow * 128 + gs * 8 + (m16 & 7)] = (bf16_t)pv;
      }
    bf16x8 pf[4];
    #pragma unroll
    for (int ksub = 0; ksub < 4; ++ksub) {
      const int g = ksub * 4 + quad;
      const int gs = (g & 8) | ((g & 7) ^ (m16 & 7));
      pf[ksub] = *(const bf16x8*)&Ps[wid][m16 * 128 + gs * 8];
    }
    #pragma unroll
    for (int dt = 0; dt < 4; ++dt) {
      const int n = dt * 16 + m16;
      #pragma unroll
      for (int ksub = 0; ksub < 4; ++ksub) {
        const int g = ksub * 4 + quad;
        const int gs = (g & 8) | ((g & 7) ^ (n & 7));
        bf16x8 vf = *(const bf16x8*)&Vs[n * 128 + gs * 8];
        oacc[dt] = __builtin_amdgcn_mfma_f32_16x16x32_bf16(pf[ksub], vf, oacc[dt], 0, 0, 0);
      }
    }
  }
  #pragma unroll
  for (int r = 0; r < 4; ++r) {
    rs[r] += __shfl_xor(rs[r], 1);
    rs[r] += __shfl_xor(rs[r], 2);
    rs[r] += __shfl_xor(rs[r], 4);
    rs[r] += __shfl_xor(rs[r], 8);
  }
  const size_t obase = ((size_t)(b * 1024 + qt * 64 + wid * 16)) * 1024 + h * 64;
  #pragma unroll
  for (int dt = 0; dt < 4; ++dt)
    #pragma unroll
    for (int r = 0; r < 4; ++r)
      O[obase + (size_t)(quad * 4 + r) * 1024 + dt * 16 + m16] = (bf16_t)(oacc[dt][r] / rs[r]);
}

// ---------------- segmented fp32 -> bf16 conversion ----------------
struct Segs {
  const float* s[5];
  bf16_t* d[5];
  int n8[5];
};
__global__ __launch_bounds__(256)
void conv_multi(Segs sg) {
  const int zz = blockIdx.z;
  const float* in = sg.s[zz];
  bf16_t* out = sg.d[zz];
  const int n8 = sg.n8[zz];
  for (int i = blockIdx.x * 256 + threadIdx.x; i < n8; i += gridDim.x * 256) {
    const float* p = in + (size_t)i * 8;
    floatx4 a = *(const floatx4*)p;
    floatx4 b = *(const floatx4*)(p + 4);
    bf16x8 o;
    #pragma unroll
    for (int j = 0; j < 4; ++j) { o[j] = (bf16_t)a[j]; o[4 + j] = (bf16_t)b[j]; }
    *(bf16x8*)(out + (size_t)i * 8) = o;
  }
}

// ---------------- LN1 with split-K combine: in = p0 + p1 + resid ----------------
__global__ __launch_bounds__(256)
void ln_combine(const bf16_t* __restrict__ p0, const bf16_t* __restrict__ p1,
                const bf16_t* __restrict__ resid,
                const float* __restrict__ g, const float* __restrict__ b,
                bf16_t* __restrict__ out) {
  const int row = blockIdx.x * 4 + (threadIdx.x >> 6);
  const int lane = threadIdx.x & 63;
  const size_t base = (size_t)row * 1024 + lane * 16;
  bf16x8 a0 = *(const bf16x8*)&p0[base];
  bf16x8 a1 = *(const bf16x8*)&p0[base + 8];
  bf16x8 b0 = *(const bf16x8*)&p1[base];
  bf16x8 b1 = *(const bf16x8*)&p1[base + 8];
  bf16x8 c0 = *(const bf16x8*)&resid[base];
  bf16x8 c1 = *(const bf16x8*)&resid[base + 8];
  float f[16];
  #pragma unroll
  for (int j = 0; j < 8; ++j) {
    f[j]     = (float)a0[j] + (float)b0[j] + (float)c0[j];
    f[8 + j] = (float)a1[j] + (float)b1[j] + (float)c1[j];
  }
  float s = 0.f, ss = 0.f;
  #pragma unroll
  for (int j = 0; j < 16; ++j) { s += f[j]; ss += f[j] * f[j]; }
  #pragma unroll
  for (int off = 1; off < 64; off <<= 1) { s += __shfl_xor(s, off); ss += __shfl_xor(ss, off); }
  const float m = s * (1.f / 1024.f);
  const float inv_sd = rsqrtf(ss * (1.f / 1024.f) - m * m + 1e-5f);
  const float* gp = g + lane * 16;
  const float* bp = b + lane * 16;
  bf16x8 o0, o1;
  #pragma unroll
  for (int j = 0; j < 8; ++j) o0[j] = (bf16_t)((f[j] - m) * inv_sd * gp[j] + bp[j]);
  #pragma unroll
  for (int j = 0; j < 8; ++j) o1[j] = (bf16_t)((f[8 + j] - m) * inv_sd * gp[8 + j] + bp[8 + j]);
  *(bf16x8*)&out[base] = o0;
  *(bf16x8*)&out[base + 8] = o1;
}

// ---- fused: (W2 combine + b2 + resid) -> LN2 -> x2; quantum -> z; ql2w conv ----
__global__ __launch_bounds__(256)
void ln2_quantum(const bf16_t* __restrict__ p0, const bf16_t* __restrict__ p1,
                 const bf16_t* __restrict__ resid, const float* __restrict__ bias,
                 const float* __restrict__ g, const float* __restrict__ b,
                 bf16_t* __restrict__ x2,
                 const float* __restrict__ qw1, const float* __restrict__ qb1,
                 const float* __restrict__ qwt, bf16_t* __restrict__ zout,
                 const float* __restrict__ ql2w, bf16_t* __restrict__ ql2wb) {
  if (blockIdx.z == 1) {
    const int n8 = 1024 * 1032 / 8;
    for (int i = blockIdx.x * 256 + threadIdx.x; i < n8; i += gridDim.x * 256) {
      const float* p = ql2w + (size_t)i * 8;
      floatx4 a = *(const floatx4*)p;
      floatx4 bb = *(const floatx4*)(p + 4);
      bf16x8 o;
      #pragma unroll
      for (int j = 0; j < 4; ++j) { o[j] = (bf16_t)a[j]; o[4 + j] = (bf16_t)bb[j]; }
      *(bf16x8*)(ql2wb + (size_t)i * 8) = o;
    }
    return;
  }
  const int row = blockIdx.x * 4 + (threadIdx.x >> 6);
  const int lane = threadIdx.x & 63;
  const size_t base = (size_t)row * 1024 + lane * 16;
  bf16x8 a0 = *(const bf16x8*)&p0[base];
  bf16x8 a1 = *(const bf16x8*)&p0[base + 8];
  bf16x8 b0 = *(const bf16x8*)&p1[base];
  bf16x8 b1 = *(const bf16x8*)&p1[base + 8];
  bf16x8 c0 = *(const bf16x8*)&resid[base];
  bf16x8 c1 = *(const bf16x8*)&resid[base + 8];
  const float* bsp = bias + lane * 16;
  float f[16];
  #pragma unroll
  for (int j = 0; j < 8; ++j) {
    f[j]     = (float)a0[j] + (float)b0[j] + (float)c0[j] + bsp[j];
    f[8 + j] = (float)a1[j] + (float)b1[j] + (float)c1[j] + bsp[8 + j];
  }
  float s = 0.f, ss = 0.f;
  #pragma unroll
  for (int j = 0; j < 16; ++j) { s += f[j]; ss += f[j] * f[j]; }
  #pragma unroll
  for (int off = 1; off < 64; off <<= 1) { s += __shfl_xor(s, off); ss += __shfl_xor(ss, off); }
  const float m = s * (1.f / 1024.f);
  const float inv_sd = rsqrtf(ss * (1.f / 1024.f) - m * m + 1e-5f);
  const float* gp = g + lane * 16;
  const float* bp = b + lane * 16;
  bf16x8 o0, o1;
  #pragma unroll
  for (int j = 0; j < 8; ++j) o0[j] = (bf16_t)((f[j] - m) * inv_sd * gp[j] + bp[j]);
  #pragma unroll
  for (int j = 0; j < 8; ++j) o1[j] = (bf16_t)((f[8 + j] - m) * inv_sd * gp[8 + j] + bp[8 + j]);
  *(bf16x8*)&x2[base] = o0;
  *(bf16x8*)&x2[base + 8] = o1;
  float th[8];
  #pragma unroll
  for (int qq = 0; qq < 8; ++qq) {
    const float* wp = qw1 + (size_t)qq * 1024 + lane * 16;
    float sdot = 0.f;
    #pragma unroll
    for (int j = 0; j < 8; ++j)
      sdot += (float)o0[j] * wp[j] + (float)o1[j] * wp[8 + j];
    #pragma unroll
    for (int off = 1; off < 64; off <<= 1) sdot += __shfl_xor(sdot, off);
    th[qq] = sdot + qb1[qq] + qwt[qq];
  }
  if (lane == 0) {
    float c[8];
    #pragma unroll
    for (int qq = 0; qq < 8; ++qq) c[qq] = cosf(th[qq]);
    float z0 = 1.f;
    #pragma unroll
    for (int u = 1; u < 8; ++u) z0 *= c[u];
    zout[(size_t)row * 8 + 0] = (bf16_t)z0;
    float pp = c[0];
    #pragma unroll
    for (int w = 1; w < 8; ++w) { pp *= c[w]; zout[(size_t)row * 8 + w] = (bf16_t)pp; }
  }
}

extern "C" void kernel_launch(void* const* d_in, const int* in_sizes, int n_in,
                              void* d_out, int out_size, void* d_ws, size_t ws_size,
                              hipStream_t stream) {
  const float* x    = (const float*)d_in[0];
  const float* Wq   = (const float*)d_in[1];
  const float* Wk   = (const float*)d_in[2];
  const float* Wv   = (const float*)d_in[3];
  const float* Wo   = (const float*)d_in[4];
  const float* ln1g = (const float*)d_in[5];
  const float* ln1b = (const float*)d_in[6];
  const float* W1   = (const float*)d_in[7];
  const float* b1   = (const float*)d_in[8];
  const float* W2   = (const float*)d_in[9];
  const float* b2   = (const float*)d_in[10];
  const float* ln2g = (const float*)d_in[11];
  const float* ln2b = (const float*)d_in[12];
  const float* qw1  = (const float*)d_in[13];
  const float* qb1  = (const float*)d_in[14];
  const float* qwt  = (const float*)d_in[15];
  const float* ql2w = (const float*)d_in[16];
  const float* ql2b = (const float*)d_in[17];
  bf16_t* ws = (bf16_t*)d_ws;

  const size_t T = (size_t)4096 * 1024;
  const size_t M1 = (size_t)1024 * 1024;
  bf16_t* outlo = (bf16_t*)d_out;
  bf16_t* outhi = outlo + T;

  bf16_t* xb    = ws;            // x bf16; resid for LN1; then W2 partial p0
  bf16_t* kb    = ws + T;        // K; Wo partial p1; then w2b; then z
  bf16_t* vt    = ws + 2 * T;    // V^T; then w1b; then W2 partial p1 / x2
  bf16_t* ff    = ws + 3 * T;    // wqkvb+wob; then FFN hidden; then ql2wb
  bf16_t* wqkvb = ff;
  bf16_t* wob   = ff + 3 * M1;
  bf16_t* w1b   = vt;
  bf16_t* w2b   = kb;
  bf16_t* ql2wb = ff;
  bf16_t* q     = outlo;
  bf16_t* o     = outhi;
  bf16_t* x1    = outhi;         // LN1 out (o dead)
  bf16_t* x2    = vt;            // LN2 out (in-place over W2 p1)
  bf16_t* z     = kb;

  {
    Segs sg;
    sg.s[0] = x;  sg.d[0] = xb;            sg.n8[0] = (int)(T / 8);
    sg.s[1] = Wq; sg.d[1] = wqkvb;         sg.n8[1] = (int)(M1 / 8);
    sg.s[2] = Wk; sg.d[2] = wqkvb + M1;    sg.n8[2] = (int)(M1 / 8);
    sg.s[3] = Wv; sg.d[3] = wqkvb + 2*M1;  sg.n8[3] = (int)(M1 / 8);
    sg.s[4] = Wo; sg.d[4] = wob;           sg.n8[4] = (int)(M1 / 8);
    conv_multi<<<dim3(512, 1, 5), 256, 0, stream>>>(sg);
  }
  gemm_qkv<<<dim3(8, 32, 3), 256, 0, stream>>>(xb, wqkvb, q, kb, vt);
  attn_kernel<<<dim3(16, 64), 256, 0, stream>>>(q, kb, vt, o);
  // Wo split-K=2 on 128x128 tile: partials outlo (q dead) + kb (K dead).
  gemm128_sk<<<512, 256, 0, stream>>>(o, wob, outlo, kb, 1024, 1024, 1024, 32, 8);
  ln_combine<<<1024, 256, 0, stream>>>(outlo, kb, xb, ln1g, ln1b, x1);
  {
    Segs sg;
    sg.s[0] = W1; sg.d[0] = w1b; sg.n8[0] = (int)(T / 8);
    sg.s[1] = W2; sg.d[1] = w2b; sg.n8[1] = (int)(T / 8);
    sg.s[2] = nullptr; sg.d[2] = nullptr; sg.n8[2] = 0;
    sg.s[3] = nullptr; sg.d[3] = nullptr; sg.n8[3] = 0;
    sg.s[4] = nullptr; sg.d[4] = nullptr; sg.n8[4] = 0;
    conv_multi<<<dim3(1024, 1, 2), 256, 0, stream>>>(sg);
  }
  gemm128<EPI_BIAS_RELU><<<dim3(32, 32), 256, 0, stream>>>(x1, w1b, ff, b1, 4096, 1024);
  // W2 split-K=2 on 128x128 tile: partials xb (x dead) + vt (w1b dead).
  gemm128_sk<<<512, 256, 0, stream>>>(ff, w2b, xb, vt, 1024, 4096, 4096, 32, 8);
  ln2_quantum<<<dim3(1024, 1, 2), 256, 0, stream>>>(
      xb, vt, x1, b2, ln2g, ln2b, x2, qw1, qb1, qwt, z, ql2w, ql2wb);
  gemm64<EPI_QL2, true><<<512, 256, 0, stream>>>(
      x2, ql2wb, d_out, nullptr, ql2b, z, ql2w, 1024, 1024, 1032, 8, 32);
}